// Round 1
// baseline (1397.202 us; speedup 1.0000x reference)
//
#include <hip/hip_runtime.h>

#define ALPHA 0.2f
#define NFEAT 256
#define NHID 64
#define NHEADS 3
#define NCLASS 40

__device__ __forceinline__ float lrelu_negexp(float x) {
    float l = x > 0.f ? x : ALPHA * x;
    return __expf(-l);
}
__device__ __forceinline__ float elu1(float x) {
    return x > 0.f ? x : (__expf(x) - 1.f);
}

// ---------------- GEMM1: h1[N,192] = x[N,256] @ W[head][256][64] ----------------
// 128x64 block tile per (blockIdx.x, head), 256 threads, 8x4 micro-tile.
__global__ __launch_bounds__(256) void gemm1_k(const float* __restrict__ x,
        const float* __restrict__ W, float* __restrict__ h1, int N) {
    __shared__ float As[16][132];   // [k][row], padded
    __shared__ float Bs[16][68];    // [k][col], padded
    const int tid = threadIdx.x;
    const int tx = tid & 15, ty = tid >> 4;
    const int head = blockIdx.y;
    const int row0 = blockIdx.x * 128;
    const float* Wb = W + (size_t)head * NFEAT * NHID;

    const int la_r = tid >> 1;          // 0..127
    const int la_k = (tid & 1) * 8;     // 0 or 8
    const int lb_k = tid >> 4;          // 0..15
    const int lb_c = (tid & 15) * 4;    // 0..60

    float acc[8][4];
#pragma unroll
    for (int i = 0; i < 8; ++i)
#pragma unroll
        for (int j = 0; j < 4; ++j) acc[i][j] = 0.f;

    int ar = row0 + la_r; if (ar >= N) ar = N - 1;
    const float* aptr = x + (size_t)ar * NFEAT + la_k;

    for (int k0 = 0; k0 < NFEAT; k0 += 16) {
        float4 av0 = *(const float4*)(aptr + k0);
        float4 av1 = *(const float4*)(aptr + k0 + 4);
        float4 bv  = *(const float4*)(Wb + (size_t)(k0 + lb_k) * NHID + lb_c);
        As[la_k+0][la_r] = av0.x; As[la_k+1][la_r] = av0.y;
        As[la_k+2][la_r] = av0.z; As[la_k+3][la_r] = av0.w;
        As[la_k+4][la_r] = av1.x; As[la_k+5][la_r] = av1.y;
        As[la_k+6][la_r] = av1.z; As[la_k+7][la_r] = av1.w;
        *(float4*)&Bs[lb_k][lb_c] = bv;
        __syncthreads();
#pragma unroll
        for (int kk = 0; kk < 16; ++kk) {
            float a[8], b[4];
#pragma unroll
            for (int i = 0; i < 8; ++i) a[i] = As[kk][ty*8+i];
#pragma unroll
            for (int j = 0; j < 4; ++j) b[j] = Bs[kk][tx*4+j];
#pragma unroll
            for (int i = 0; i < 8; ++i)
#pragma unroll
                for (int j = 0; j < 4; ++j)
                    acc[i][j] = fmaf(a[i], b[j], acc[i][j]);
        }
        __syncthreads();
    }
#pragma unroll
    for (int i = 0; i < 8; ++i) {
        int r = row0 + ty*8 + i;
        if (r < N) {
            float4 v = make_float4(acc[i][0], acc[i][1], acc[i][2], acc[i][3]);
            *(float4*)(h1 + (size_t)r*(NHEADS*NHID) + head*NHID + tx*4) = v;
        }
    }
}

// ---------------- per-node logit dots, layer 1 ----------------
__global__ __launch_bounds__(256) void dots1_k(const float* __restrict__ h1,
        const float* __restrict__ a1, const float* __restrict__ a2,
        float* __restrict__ ad, float* __restrict__ as_, int N) {
    int gt = blockIdx.x * 256 + threadIdx.x;
    int wid = gt >> 6, lane = gt & 63;
    if (wid >= N) return;
    const float* hr = h1 + (size_t)wid * 192;
#pragma unroll
    for (int k = 0; k < 3; ++k) {
        float v = hr[k*64 + lane];
        float da = v * a1[k*64 + lane];
        float db = v * a2[k*64 + lane];
#pragma unroll
        for (int o = 32; o > 0; o >>= 1) {
            da += __shfl_down(da, o, 64);
            db += __shfl_down(db, o, 64);
        }
        if (lane == 0) { ad[wid*3+k] = da; as_[wid*3+k] = db; }
    }
}

// ---------------- CSR build ----------------
__global__ __launch_bounds__(256) void hist_k(const int* __restrict__ dst,
        int* __restrict__ cnt, int E) {
    int e = blockIdx.x * 256 + threadIdx.x;
    if (e < E) atomicAdd(&cnt[dst[e]], 1);
}

__global__ __launch_bounds__(256) void scan1_k(const int* __restrict__ cnt,
        int* __restrict__ part, int* __restrict__ sums, int N) {
    __shared__ int s[256];
    int tid = threadIdx.x, b = blockIdx.x;
    int base = b * 2048 + tid * 8;
    int v[8]; int t = 0;
#pragma unroll
    for (int i = 0; i < 8; ++i) { int idx = base + i; v[i] = (idx < N) ? cnt[idx] : 0; t += v[i]; }
    s[tid] = t; __syncthreads();
    for (int o = 1; o < 256; o <<= 1) {
        int u = (tid >= o) ? s[tid - o] : 0;
        __syncthreads();
        s[tid] += u;
        __syncthreads();
    }
    int run = s[tid] - t;   // exclusive
#pragma unroll
    for (int i = 0; i < 8; ++i) { int idx = base + i; if (idx < N) part[idx] = run; run += v[i]; }
    if (tid == 255) sums[b] = s[255];
}

__global__ void scan2_k(int* sums, int nb) {
    if (threadIdx.x == 0 && blockIdx.x == 0) {
        int run = 0;
        for (int i = 0; i < nb; ++i) { int t = sums[i]; sums[i] = run; run += t; }
    }
}

__global__ __launch_bounds__(256) void scan3_k(const int* __restrict__ part,
        const int* __restrict__ sums, int* __restrict__ ptr, int N, int E) {
    int i = blockIdx.x * 256 + threadIdx.x;
    if (i < N) ptr[i] = part[i] + sums[i >> 11];
    if (i == 0) ptr[N] = E;
}

__global__ __launch_bounds__(256) void scatter_k(const int* __restrict__ dst,
        const int* __restrict__ src, const int* __restrict__ ptr,
        int* __restrict__ fill, int* __restrict__ csr, int E) {
    int e = blockIdx.x * 256 + threadIdx.x;
    if (e < E) {
        int d = dst[e];
        int pos = ptr[d] + atomicAdd(&fill[d], 1);
        csr[pos] = src[e];
    }
}

// ---------------- layer-1 aggregation: wave per node, lane = feature ----------------
__global__ __launch_bounds__(256) void agg1_k(const float* __restrict__ h1,
        const float* __restrict__ ad, const float* __restrict__ as_,
        const int* __restrict__ ptr, const int* __restrict__ csr,
        float* __restrict__ out1, int N) {
    int gt = blockIdx.x * 256 + threadIdx.x;
    int wid = gt >> 6, lane = gt & 63;
    if (wid >= N) return;
    int p0 = ptr[wid], p1 = ptr[wid + 1];
    float ad0 = ad[wid*3], ad1v = ad[wid*3+1], ad2v = ad[wid*3+2];
    float acc0 = 0, acc1 = 0, acc2 = 0, den0 = 0, den1 = 0, den2 = 0;
    for (int p = p0; p < p1; ++p) {
        int s = csr[p];
        const float* hs = h1 + (size_t)s * 192;
        float e0 = lrelu_negexp(ad0  + as_[s*3+0]);
        float e1 = lrelu_negexp(ad1v + as_[s*3+1]);
        float e2 = lrelu_negexp(ad2v + as_[s*3+2]);
        acc0 = fmaf(e0, hs[lane],      acc0);
        acc1 = fmaf(e1, hs[64 + lane], acc1);
        acc2 = fmaf(e2, hs[128 + lane], acc2);
        den0 += e0; den1 += e1; den2 += e2;
    }
    size_t ob = (size_t)wid * 192;
    out1[ob + lane]        = elu1(acc0 / (den0 + 1e-16f));
    out1[ob + 64 + lane]   = elu1(acc1 / (den1 + 1e-16f));
    out1[ob + 128 + lane]  = elu1(acc2 / (den2 + 1e-16f));
}

// ---------------- GEMM2: h2[N,40] = out1[N,192] @ Wo[192,40] ----------------
__global__ __launch_bounds__(256) void gemm2_k(const float* __restrict__ X,
        const float* __restrict__ Wo, float* __restrict__ h2, int N) {
    __shared__ float Xs[32][193];
    __shared__ float Ws[192 * 40];
    const int tid = threadIdx.x;
    const int row0 = blockIdx.x * 32;
    for (int i = tid; i < 192 * 40; i += 256) Ws[i] = Wo[i];
    for (int i = tid; i < 32 * 48; i += 256) {
        int r = i / 48, c4 = (i % 48) * 4;
        int rr = row0 + r; if (rr >= N) rr = N - 1;
        float4 v = *(const float4*)(X + (size_t)rr * 192 + c4);
        Xs[r][c4+0] = v.x; Xs[r][c4+1] = v.y; Xs[r][c4+2] = v.z; Xs[r][c4+3] = v.w;
    }
    __syncthreads();
    int rsub = tid >> 3;          // 0..31
    int f0 = (tid & 7) * 5;       // 0..35
    float acc[5] = {0, 0, 0, 0, 0};
    for (int c = 0; c < 192; ++c) {
        float xv = Xs[rsub][c];
#pragma unroll
        for (int j = 0; j < 5; ++j) acc[j] = fmaf(xv, Ws[c*40 + f0 + j], acc[j]);
    }
    int r = row0 + rsub;
    if (r < N) {
#pragma unroll
        for (int j = 0; j < 5; ++j) h2[(size_t)r*40 + f0 + j] = acc[j];
    }
}

// ---------------- per-node logit dots, layer 2 ----------------
__global__ __launch_bounds__(256) void dots2_k(const float* __restrict__ h2,
        const float* __restrict__ a1o, const float* __restrict__ a2o,
        float* __restrict__ ad2, float* __restrict__ as2, int N) {
    int gt = blockIdx.x * 256 + threadIdx.x;
    int wid = gt >> 6, lane = gt & 63;
    if (wid >= N) return;
    float v = 0.f, w1 = 0.f, w2 = 0.f;
    if (lane < 40) { v = h2[(size_t)wid*40 + lane]; w1 = a1o[lane]; w2 = a2o[lane]; }
    float da = v * w1, db = v * w2;
#pragma unroll
    for (int o = 32; o > 0; o >>= 1) { da += __shfl_down(da, o, 64); db += __shfl_down(db, o, 64); }
    if (lane == 0) { ad2[wid] = da; as2[wid] = db; }
}

// ---------------- layer-2 aggregation + final ELU ----------------
__global__ __launch_bounds__(256) void agg2_k(const float* __restrict__ h2,
        const float* __restrict__ ad2, const float* __restrict__ as2,
        const int* __restrict__ ptr, const int* __restrict__ csr,
        float* __restrict__ out, int N) {
    int gt = blockIdx.x * 256 + threadIdx.x;
    int wid = gt >> 6, lane = gt & 63;
    if (wid >= N) return;
    int p0 = ptr[wid], p1 = ptr[wid + 1];
    float adv = ad2[wid];
    float acc = 0.f, den = 0.f;
    for (int p = p0; p < p1; ++p) {
        int s = csr[p];
        float e = lrelu_negexp(adv + as2[s]);
        float hv = (lane < 40) ? h2[(size_t)s*40 + lane] : 0.f;
        acc = fmaf(e, hv, acc);
        den += e;
    }
    float o = elu1(acc / (den + 1e-16f));
    if (lane < 40) out[(size_t)wid*40 + lane] = o;
}

extern "C" void kernel_launch(void* const* d_in, const int* in_sizes, int n_in,
                              void* d_out, int out_size, void* d_ws, size_t ws_size,
                              hipStream_t stream) {
    const float* x   = (const float*)d_in[0];
    const int*   ei  = (const int*)d_in[1];
    const float* W   = (const float*)d_in[2];
    const float* a1  = (const float*)d_in[3];
    const float* a2  = (const float*)d_in[4];
    const float* Wo  = (const float*)d_in[5];
    const float* a1o = (const float*)d_in[6];
    const float* a2o = (const float*)d_in[7];
    const int N = in_sizes[0] / NFEAT;
    const int E = in_sizes[1] / 2;
    const int* dst = ei;
    const int* src = ei + E;

    char* base = (char*)d_ws;
    size_t off = 0;
    auto alloc = [&](size_t bytes) { void* p = base + off; off += (bytes + 255) & ~(size_t)255; return p; };
    float* h1   = (float*)alloc((size_t)N * 192 * 4);
    float* out1 = (float*)alloc((size_t)N * 192 * 4);
    int*   csr  = (int*)alloc((size_t)E * 4);
    int*   ptr  = (int*)alloc((size_t)(N + 1) * 4);
    int*   cnt  = (int*)alloc((size_t)N * 4);
    int*   part = (int*)alloc((size_t)N * 4);
    int*   sums = (int*)alloc(1024);
    float* ad1  = (float*)alloc((size_t)N * 3 * 4);
    float* as1  = (float*)alloc((size_t)N * 3 * 4);
    // layer-2 buffers alias the (dead after agg1) h1 region: N*42 < N*192 floats
    float* h2  = h1;
    float* ad2 = h1 + (size_t)N * 40;
    float* as2 = ad2 + N;

    hipMemsetAsync(cnt, 0, (size_t)N * 4, stream);

    dim3 g1((N + 127) / 128, NHEADS);
    gemm1_k<<<g1, 256, 0, stream>>>(x, W, h1, N);

    hist_k<<<(E + 255) / 256, 256, 0, stream>>>(dst, cnt, E);
    int nb = (N + 2047) / 2048;
    scan1_k<<<nb, 256, 0, stream>>>(cnt, part, sums, N);
    scan2_k<<<1, 64, 0, stream>>>(sums, nb);
    scan3_k<<<(N + 255) / 256, 256, 0, stream>>>(part, sums, ptr, N, E);
    hipMemsetAsync(cnt, 0, (size_t)N * 4, stream);
    scatter_k<<<(E + 255) / 256, 256, 0, stream>>>(dst, src, ptr, cnt, csr, E);

    dots1_k<<<(N + 3) / 4, 256, 0, stream>>>(h1, a1, a2, ad1, as1, N);
    agg1_k<<<(N + 3) / 4, 256, 0, stream>>>(h1, ad1, as1, ptr, csr, out1, N);

    gemm2_k<<<(N + 31) / 32, 256, 0, stream>>>(out1, Wo, h2, N);
    dots2_k<<<(N + 3) / 4, 256, 0, stream>>>(h2, a1o, a2o, ad2, as2, N);
    agg2_k<<<(N + 3) / 4, 256, 0, stream>>>(h2, ad2, as2, ptr, csr, (float*)d_out, N);
}

// Round 2
// 1332.552 us; speedup vs baseline: 1.0485x; 1.0485x over previous
//
#include <hip/hip_runtime.h>

#define ALPHA 0.2f
#define NFEAT 256
#define NHID 64
#define NHEADS 3
#define NCLASS 40

__device__ __forceinline__ float lrelu_negexp(float x) {
    float l = x > 0.f ? x : ALPHA * x;
    return __expf(-l);
}
__device__ __forceinline__ float elu1(float x) {
    return x > 0.f ? x : (__expf(x) - 1.f);
}

// ---------------- GEMM1: h1[N,192] = x[N,256] @ W[head][256][64] ----------------
__global__ __launch_bounds__(256) void gemm1_k(const float* __restrict__ x,
        const float* __restrict__ W, float* __restrict__ h1, int N) {
    __shared__ float As[16][132];
    __shared__ float Bs[16][68];
    const int tid = threadIdx.x;
    const int tx = tid & 15, ty = tid >> 4;
    const int head = blockIdx.y;
    const int row0 = blockIdx.x * 128;
    const float* Wb = W + (size_t)head * NFEAT * NHID;

    const int la_r = tid >> 1;
    const int la_k = (tid & 1) * 8;
    const int lb_k = tid >> 4;
    const int lb_c = (tid & 15) * 4;

    float acc[8][4];
#pragma unroll
    for (int i = 0; i < 8; ++i)
#pragma unroll
        for (int j = 0; j < 4; ++j) acc[i][j] = 0.f;

    int ar = row0 + la_r; if (ar >= N) ar = N - 1;
    const float* aptr = x + (size_t)ar * NFEAT + la_k;

    for (int k0 = 0; k0 < NFEAT; k0 += 16) {
        float4 av0 = *(const float4*)(aptr + k0);
        float4 av1 = *(const float4*)(aptr + k0 + 4);
        float4 bv  = *(const float4*)(Wb + (size_t)(k0 + lb_k) * NHID + lb_c);
        As[la_k+0][la_r] = av0.x; As[la_k+1][la_r] = av0.y;
        As[la_k+2][la_r] = av0.z; As[la_k+3][la_r] = av0.w;
        As[la_k+4][la_r] = av1.x; As[la_k+5][la_r] = av1.y;
        As[la_k+6][la_r] = av1.z; As[la_k+7][la_r] = av1.w;
        *(float4*)&Bs[lb_k][lb_c] = bv;
        __syncthreads();
#pragma unroll
        for (int kk = 0; kk < 16; ++kk) {
            float a[8], b[4];
#pragma unroll
            for (int i = 0; i < 8; ++i) a[i] = As[kk][ty*8+i];
#pragma unroll
            for (int j = 0; j < 4; ++j) b[j] = Bs[kk][tx*4+j];
#pragma unroll
            for (int i = 0; i < 8; ++i)
#pragma unroll
                for (int j = 0; j < 4; ++j)
                    acc[i][j] = fmaf(a[i], b[j], acc[i][j]);
        }
        __syncthreads();
    }
#pragma unroll
    for (int i = 0; i < 8; ++i) {
        int r = row0 + ty*8 + i;
        if (r < N) {
            float4 v = make_float4(acc[i][0], acc[i][1], acc[i][2], acc[i][3]);
            *(float4*)(h1 + (size_t)r*(NHEADS*NHID) + head*NHID + tx*4) = v;
        }
    }
}

// ---------------- per-node logit dots, layer 1 ----------------
__global__ __launch_bounds__(256) void dots1_k(const float* __restrict__ h1,
        const float* __restrict__ a1, const float* __restrict__ a2,
        float* __restrict__ ad, float* __restrict__ as_, int N) {
    int gt = blockIdx.x * 256 + threadIdx.x;
    int wid = gt >> 6, lane = gt & 63;
    if (wid >= N) return;
    const float* hr = h1 + (size_t)wid * 192;
#pragma unroll
    for (int k = 0; k < 3; ++k) {
        float v = hr[k*64 + lane];
        float da = v * a1[k*64 + lane];
        float db = v * a2[k*64 + lane];
#pragma unroll
        for (int o = 32; o > 0; o >>= 1) {
            da += __shfl_down(da, o, 64);
            db += __shfl_down(db, o, 64);
        }
        if (lane == 0) { ad[wid*3+k] = da; as_[wid*3+k] = db; }
    }
}

// ---------------- CSR build ----------------
__global__ __launch_bounds__(256) void hist_k(const int* __restrict__ dst,
        int* __restrict__ cnt, int E) {
    int e = blockIdx.x * 256 + threadIdx.x;
    if (e < E) atomicAdd(&cnt[dst[e]], 1);
}

__global__ __launch_bounds__(256) void scan1_k(const int* __restrict__ cnt,
        int* __restrict__ part, int* __restrict__ sums, int N) {
    __shared__ int s[256];
    int tid = threadIdx.x, b = blockIdx.x;
    int base = b * 2048 + tid * 8;
    int v[8]; int t = 0;
#pragma unroll
    for (int i = 0; i < 8; ++i) { int idx = base + i; v[i] = (idx < N) ? cnt[idx] : 0; t += v[i]; }
    s[tid] = t; __syncthreads();
    for (int o = 1; o < 256; o <<= 1) {
        int u = (tid >= o) ? s[tid - o] : 0;
        __syncthreads();
        s[tid] += u;
        __syncthreads();
    }
    int run = s[tid] - t;
#pragma unroll
    for (int i = 0; i < 8; ++i) { int idx = base + i; if (idx < N) part[idx] = run; run += v[i]; }
    if (tid == 255) sums[b] = s[255];
}

__global__ void scan2_k(int* sums, int nb) {
    if (threadIdx.x == 0 && blockIdx.x == 0) {
        int run = 0;
        for (int i = 0; i < nb; ++i) { int t = sums[i]; sums[i] = run; run += t; }
    }
}

__global__ __launch_bounds__(256) void scan3_k(const int* __restrict__ part,
        const int* __restrict__ sums, int* __restrict__ ptr, int N, int E) {
    int i = blockIdx.x * 256 + threadIdx.x;
    if (i < N) ptr[i] = part[i] + sums[i >> 11];
    if (i == 0) ptr[N] = E;
}

__global__ __launch_bounds__(256) void scatter_k(const int* __restrict__ dst,
        const int* __restrict__ src, const int* __restrict__ ptr,
        int* __restrict__ fill, int* __restrict__ csr,
        int* __restrict__ rowid, int E) {
    int e = blockIdx.x * 256 + threadIdx.x;
    if (e < E) {
        int d = dst[e];
        int pos = ptr[d] + atomicAdd(&fill[d], 1);
        csr[pos] = src[e];
        rowid[pos] = d;
    }
}

// ---------------- edge weights, layer 1 (pos-parallel, coalesced) ----------------
__global__ __launch_bounds__(256) void edgew1_k(const int* __restrict__ rowid,
        const int* __restrict__ csr, const float* __restrict__ ad,
        const float* __restrict__ as_, float4* __restrict__ w4, int E) {
    int i = blockIdx.x * 256 + threadIdx.x;
    if (i >= E) return;
    int d = rowid[i], s = csr[i];
    float e0 = lrelu_negexp(ad[d*3+0] + as_[s*3+0]);
    float e1 = lrelu_negexp(ad[d*3+1] + as_[s*3+1]);
    float e2 = lrelu_negexp(ad[d*3+2] + as_[s*3+2]);
    w4[i] = make_float4(e0, e1, e2, 0.f);
}

// ---------------- layer-1 aggregation: wave per node, software-pipelined ----------------
__global__ __launch_bounds__(256) void agg1_k(const float* __restrict__ h1,
        const float4* __restrict__ w4,
        const int* __restrict__ ptr, const int* __restrict__ csr,
        float* __restrict__ out1, int N) {
    int gt = blockIdx.x * 256 + threadIdx.x;
    int wid = gt >> 6, lane = gt & 63;
    if (wid >= N) return;
    int p0 = ptr[wid], p1 = ptr[wid + 1];
    float acc0 = 0, acc1 = 0, acc2 = 0, den0 = 0, den1 = 0, den2 = 0;

    // pipeline: h row for edge p in regs; index/weight for edge p+1 in regs
    int sA = csr[p0];
    float4 wA = w4[p0];
    const float* hA = h1 + (size_t)sA * 192;
    float va = hA[lane], vb = hA[64 + lane], vc = hA[128 + lane];
    int sB = 0; float4 wB = wA;
    if (p0 + 1 < p1) { sB = csr[p0 + 1]; wB = w4[p0 + 1]; }

    for (int p = p0; p < p1; ++p) {
        float ca = va, cb = vb, cc = vc;
        float4 cw = wA;
        if (p + 1 < p1) {
            const float* hB = h1 + (size_t)sB * 192;
            va = hB[lane]; vb = hB[64 + lane]; vc = hB[128 + lane];
            wA = wB;
            if (p + 2 < p1) { sB = csr[p + 2]; wB = w4[p + 2]; }
        }
        acc0 = fmaf(cw.x, ca, acc0);
        acc1 = fmaf(cw.y, cb, acc1);
        acc2 = fmaf(cw.z, cc, acc2);
        den0 += cw.x; den1 += cw.y; den2 += cw.z;
    }
    size_t ob = (size_t)wid * 192;
    out1[ob + lane]       = elu1(acc0 / (den0 + 1e-16f));
    out1[ob + 64 + lane]  = elu1(acc1 / (den1 + 1e-16f));
    out1[ob + 128 + lane] = elu1(acc2 / (den2 + 1e-16f));
}

// ---------------- GEMM2: h2[N,40] = out1[N,192] @ Wo[192,40] ----------------
__global__ __launch_bounds__(256) void gemm2_k(const float* __restrict__ X,
        const float* __restrict__ Wo, float* __restrict__ h2, int N) {
    __shared__ float Xs[32][193];
    __shared__ float Ws[192 * 40];
    const int tid = threadIdx.x;
    const int row0 = blockIdx.x * 32;
    for (int i = tid; i < 192 * 40; i += 256) Ws[i] = Wo[i];
    for (int i = tid; i < 32 * 48; i += 256) {
        int r = i / 48, c4 = (i % 48) * 4;
        int rr = row0 + r; if (rr >= N) rr = N - 1;
        float4 v = *(const float4*)(X + (size_t)rr * 192 + c4);
        Xs[r][c4+0] = v.x; Xs[r][c4+1] = v.y; Xs[r][c4+2] = v.z; Xs[r][c4+3] = v.w;
    }
    __syncthreads();
    int rsub = tid >> 3;
    int f0 = (tid & 7) * 5;
    float acc[5] = {0, 0, 0, 0, 0};
    for (int c = 0; c < 192; ++c) {
        float xv = Xs[rsub][c];
#pragma unroll
        for (int j = 0; j < 5; ++j) acc[j] = fmaf(xv, Ws[c*40 + f0 + j], acc[j]);
    }
    int r = row0 + rsub;
    if (r < N) {
#pragma unroll
        for (int j = 0; j < 5; ++j) h2[(size_t)r*40 + f0 + j] = acc[j];
    }
}

// ---------------- per-node logit dots, layer 2 ----------------
__global__ __launch_bounds__(256) void dots2_k(const float* __restrict__ h2,
        const float* __restrict__ a1o, const float* __restrict__ a2o,
        float* __restrict__ ad2, float* __restrict__ as2, int N) {
    int gt = blockIdx.x * 256 + threadIdx.x;
    int wid = gt >> 6, lane = gt & 63;
    if (wid >= N) return;
    float v = 0.f, w1 = 0.f, w2 = 0.f;
    if (lane < 40) { v = h2[(size_t)wid*40 + lane]; w1 = a1o[lane]; w2 = a2o[lane]; }
    float da = v * w1, db = v * w2;
#pragma unroll
    for (int o = 32; o > 0; o >>= 1) { da += __shfl_down(da, o, 64); db += __shfl_down(db, o, 64); }
    if (lane == 0) { ad2[wid] = da; as2[wid] = db; }
}

// ---------------- edge weights, layer 2 ----------------
__global__ __launch_bounds__(256) void edgew2_k(const int* __restrict__ rowid,
        const int* __restrict__ csr, const float* __restrict__ ad2,
        const float* __restrict__ as2, float* __restrict__ w2, int E) {
    int i = blockIdx.x * 256 + threadIdx.x;
    if (i >= E) return;
    w2[i] = lrelu_negexp(ad2[rowid[i]] + as2[csr[i]]);
}

// ---------------- layer-2 aggregation + final ELU, software-pipelined ----------------
__global__ __launch_bounds__(256) void agg2_k(const float* __restrict__ h2,
        const float* __restrict__ w2,
        const int* __restrict__ ptr, const int* __restrict__ csr,
        float* __restrict__ out, int N) {
    int gt = blockIdx.x * 256 + threadIdx.x;
    int wid = gt >> 6, lane = gt & 63;
    if (wid >= N) return;
    int p0 = ptr[wid], p1 = ptr[wid + 1];
    float acc = 0.f, den = 0.f;

    int sA = csr[p0];
    float wA = w2[p0];
    float hv = (lane < 40) ? h2[(size_t)sA*40 + lane] : 0.f;
    int sB = 0; float wB = wA;
    if (p0 + 1 < p1) { sB = csr[p0 + 1]; wB = w2[p0 + 1]; }

    for (int p = p0; p < p1; ++p) {
        float ch = hv;
        float cw = wA;
        if (p + 1 < p1) {
            hv = (lane < 40) ? h2[(size_t)sB*40 + lane] : 0.f;
            wA = wB;
            if (p + 2 < p1) { sB = csr[p + 2]; wB = w2[p + 2]; }
        }
        acc = fmaf(cw, ch, acc);
        den += cw;
    }
    float o = elu1(acc / (den + 1e-16f));
    if (lane < 40) out[(size_t)wid*40 + lane] = o;
}

extern "C" void kernel_launch(void* const* d_in, const int* in_sizes, int n_in,
                              void* d_out, int out_size, void* d_ws, size_t ws_size,
                              hipStream_t stream) {
    const float* x   = (const float*)d_in[0];
    const int*   ei  = (const int*)d_in[1];
    const float* W   = (const float*)d_in[2];
    const float* a1  = (const float*)d_in[3];
    const float* a2  = (const float*)d_in[4];
    const float* Wo  = (const float*)d_in[5];
    const float* a1o = (const float*)d_in[6];
    const float* a2o = (const float*)d_in[7];
    const int N = in_sizes[0] / NFEAT;
    const int E = in_sizes[1] / 2;
    const int* dst = ei;
    const int* src = ei + E;

    char* base = (char*)d_ws;
    size_t off = 0;
    auto alloc = [&](size_t bytes) { void* p = base + off; off += (bytes + 255) & ~(size_t)255; return p; };
    float*  h1    = (float*)alloc((size_t)N * 192 * 4);
    float*  out1  = (float*)alloc((size_t)N * 192 * 4);
    int*    csr   = (int*)alloc((size_t)E * 4);
    int*    rowid = (int*)alloc((size_t)E * 4);
    float4* w4    = (float4*)alloc((size_t)E * 16);
    int*    ptr   = (int*)alloc((size_t)(N + 1) * 4);
    int*    cnt   = (int*)alloc((size_t)N * 4);
    int*    part  = (int*)alloc((size_t)N * 4);
    int*    sums  = (int*)alloc(1024);
    float*  ad1   = (float*)alloc((size_t)N * 3 * 4);
    float*  as1   = (float*)alloc((size_t)N * 3 * 4);
    // layer-2 buffers alias dead regions: h2/ad2/as2 in h1; w2 in w4
    float* h2  = h1;
    float* ad2 = h1 + (size_t)N * 40;
    float* as2 = ad2 + N;
    float* w2  = (float*)w4;

    hipMemsetAsync(cnt, 0, (size_t)N * 4, stream);

    dim3 g1((N + 127) / 128, NHEADS);
    gemm1_k<<<g1, 256, 0, stream>>>(x, W, h1, N);

    hist_k<<<(E + 255) / 256, 256, 0, stream>>>(dst, cnt, E);
    int nb = (N + 2047) / 2048;
    scan1_k<<<nb, 256, 0, stream>>>(cnt, part, sums, N);
    scan2_k<<<1, 64, 0, stream>>>(sums, nb);
    scan3_k<<<(N + 255) / 256, 256, 0, stream>>>(part, sums, ptr, N, E);
    hipMemsetAsync(cnt, 0, (size_t)N * 4, stream);
    scatter_k<<<(E + 255) / 256, 256, 0, stream>>>(dst, src, ptr, cnt, csr, rowid, E);

    dots1_k<<<(N + 3) / 4, 256, 0, stream>>>(h1, a1, a2, ad1, as1, N);
    edgew1_k<<<(E + 255) / 256, 256, 0, stream>>>(rowid, csr, ad1, as1, w4, E);
    agg1_k<<<(N + 3) / 4, 256, 0, stream>>>(h1, w4, ptr, csr, out1, N);

    gemm2_k<<<(N + 31) / 32, 256, 0, stream>>>(out1, Wo, h2, N);
    dots2_k<<<(N + 3) / 4, 256, 0, stream>>>(h2, a1o, a2o, ad2, as2, N);
    edgew2_k<<<(E + 255) / 256, 256, 0, stream>>>(rowid, csr, ad2, as2, w2, E);
    agg2_k<<<(N + 3) / 4, 256, 0, stream>>>(h2, w2, ptr, csr, (float*)d_out, N);
}

// Round 3
// 1239.545 us; speedup vs baseline: 1.1272x; 1.0750x over previous
//
#include <hip/hip_runtime.h>

#define ALPHA 0.2f
#define NFEAT 256
#define NHID 64
#define NHEADS 3
#define NCLASS 40

typedef short short8 __attribute__((ext_vector_type(8)));
typedef float float4v __attribute__((ext_vector_type(4)));

__device__ __forceinline__ float lrelu_negexp(float x) {
    float l = x > 0.f ? x : ALPHA * x;
    return __expf(-l);
}
__device__ __forceinline__ float elu1(float x) {
    return x > 0.f ? x : (__expf(x) - 1.f);
}
__device__ __forceinline__ unsigned short f2bf(float f) {
    unsigned int u = __float_as_uint(f);
    unsigned int r = (u + 0x7FFFu + ((u >> 16) & 1u)) >> 16;   // RN-even
    return (unsigned short)r;
}
__device__ __forceinline__ float bf2f(unsigned short h) {
    return __uint_as_float(((unsigned int)h) << 16);
}

// ---------------- convert x -> bf16 hi/lo split ----------------
__global__ __launch_bounds__(256) void cvt_x_k(const float* __restrict__ x,
        unsigned short* __restrict__ xhi, unsigned short* __restrict__ xlo, long n4) {
    long i = (long)blockIdx.x * 256 + threadIdx.x;
    if (i >= n4) return;
    float4 v = ((const float4*)x)[i];
    ushort4 hi, lo;
    hi.x = f2bf(v.x); lo.x = f2bf(v.x - bf2f(hi.x));
    hi.y = f2bf(v.y); lo.y = f2bf(v.y - bf2f(hi.y));
    hi.z = f2bf(v.z); lo.z = f2bf(v.z - bf2f(hi.z));
    hi.w = f2bf(v.w); lo.w = f2bf(v.w - bf2f(hi.w));
    ((ushort4*)xhi)[i] = hi;
    ((ushort4*)xlo)[i] = lo;
}

// ---------------- convert + transpose W: [3][256][64] -> Wt[192][256] hi/lo ----------------
__global__ __launch_bounds__(256) void cvt_w_k(const float* __restrict__ W,
        unsigned short* __restrict__ wthi, unsigned short* __restrict__ wtlo) {
    int i = blockIdx.x * 256 + threadIdx.x;   // over 3*64*256
    if (i >= NHEADS * NHID * NFEAT) return;
    int k = i & 255, nc = (i >> 8) & 63, head = i >> 14;
    float v = W[(size_t)head * NFEAT * NHID + (size_t)k * NHID + nc];
    unsigned short hi = f2bf(v);
    unsigned short lo = f2bf(v - bf2f(hi));
    wthi[i] = hi;   // layout: [(head*64+nc)][k], k contiguous
    wtlo[i] = lo;
}

// ---------------- GEMM1 via split-bf16 MFMA ----------------
// block: 128 rows x 192 cols, 4 waves in 2x2 grid (wave tile 64M x 96N), BK=32
__global__ __launch_bounds__(256) void gemm1_mfma_k(
        const unsigned short* __restrict__ xhi, const unsigned short* __restrict__ xlo,
        const unsigned short* __restrict__ wthi, const unsigned short* __restrict__ wtlo,
        float* __restrict__ h1, int N) {
    __shared__ unsigned short Ah[128 * 40];   // padded stride 40 shorts (80 B)
    __shared__ unsigned short Al[128 * 40];
    __shared__ unsigned short Bh[192 * 40];
    __shared__ unsigned short Bl[192 * 40];
    const int tid = threadIdx.x;
    const int wave = tid >> 6, lane = tid & 63;
    const int quad = lane >> 4, l16 = lane & 15;
    const int row0 = blockIdx.x * 128;
    const int wm = (wave >> 1) * 64;
    const int wn = (wave & 1) * 96;

    float4v acc[4][6];
#pragma unroll
    for (int s = 0; s < 4; ++s)
#pragma unroll
        for (int t = 0; t < 6; ++t)
            acc[s][t] = (float4v){0.f, 0.f, 0.f, 0.f};

    for (int kc = 0; kc < NFEAT; kc += 32) {
        // stage A (128x32 hi+lo)
#pragma unroll
        for (int rr = 0; rr < 2; ++rr) {
            int idx = rr * 256 + tid;
            int r = idx >> 2, kq = (idx & 3) * 8;
            int gr = row0 + r; if (gr >= N) gr = N - 1;
            size_t g = (size_t)gr * NFEAT + kc + kq;
            *(int4*)&Ah[r * 40 + kq] = *(const int4*)(xhi + g);
            *(int4*)&Al[r * 40 + kq] = *(const int4*)(xlo + g);
        }
        // stage B (192x32 hi+lo)
#pragma unroll
        for (int rr = 0; rr < 3; ++rr) {
            int idx = rr * 256 + tid;
            int r = idx >> 2, kq = (idx & 3) * 8;
            size_t g = (size_t)r * NFEAT + kc + kq;
            *(int4*)&Bh[r * 40 + kq] = *(const int4*)(wthi + g);
            *(int4*)&Bl[r * 40 + kq] = *(const int4*)(wtlo + g);
        }
        __syncthreads();

        short8 ah[4], al[4];
#pragma unroll
        for (int s = 0; s < 4; ++s) {
            int m = wm + s * 16 + l16;
            ah[s] = *(const short8*)&Ah[m * 40 + quad * 8];
            al[s] = *(const short8*)&Al[m * 40 + quad * 8];
        }
#pragma unroll
        for (int t = 0; t < 6; ++t) {
            int n = wn + t * 16 + l16;
            short8 bh = *(const short8*)&Bh[n * 40 + quad * 8];
            short8 bl = *(const short8*)&Bl[n * 40 + quad * 8];
#pragma unroll
            for (int s = 0; s < 4; ++s) {
                acc[s][t] = __builtin_amdgcn_mfma_f32_16x16x32_bf16(ah[s], bh, acc[s][t], 0, 0, 0);
                acc[s][t] = __builtin_amdgcn_mfma_f32_16x16x32_bf16(ah[s], bl, acc[s][t], 0, 0, 0);
                acc[s][t] = __builtin_amdgcn_mfma_f32_16x16x32_bf16(al[s], bh, acc[s][t], 0, 0, 0);
            }
        }
        __syncthreads();
    }
    // epilogue: C/D layout col=lane&15, row=quad*4+r
#pragma unroll
    for (int s = 0; s < 4; ++s) {
#pragma unroll
        for (int r = 0; r < 4; ++r) {
            int grow = row0 + wm + s * 16 + quad * 4 + r;
            if (grow < N) {
#pragma unroll
                for (int t = 0; t < 6; ++t)
                    h1[(size_t)grow * 192 + wn + t * 16 + l16] = acc[s][t][r];
            }
        }
    }
}

// ---------------- per-node logit dots, layer 1 ----------------
__global__ __launch_bounds__(256) void dots1_k(const float* __restrict__ h1,
        const float* __restrict__ a1, const float* __restrict__ a2,
        float* __restrict__ ad, float* __restrict__ as_, int N) {
    int gt = blockIdx.x * 256 + threadIdx.x;
    int wid = gt >> 6, lane = gt & 63;
    if (wid >= N) return;
    const float* hr = h1 + (size_t)wid * 192;
#pragma unroll
    for (int k = 0; k < 3; ++k) {
        float v = hr[k*64 + lane];
        float da = v * a1[k*64 + lane];
        float db = v * a2[k*64 + lane];
#pragma unroll
        for (int o = 32; o > 0; o >>= 1) {
            da += __shfl_down(da, o, 64);
            db += __shfl_down(db, o, 64);
        }
        if (lane == 0) { ad[wid*3+k] = da; as_[wid*3+k] = db; }
    }
}

// ---------------- CSR build ----------------
__global__ __launch_bounds__(256) void hist_k(const int* __restrict__ dst,
        int* __restrict__ cnt, int E) {
    int e = blockIdx.x * 256 + threadIdx.x;
    if (e < E) atomicAdd(&cnt[dst[e]], 1);
}

__global__ __launch_bounds__(256) void scan1_k(const int* __restrict__ cnt,
        int* __restrict__ part, int* __restrict__ sums, int N) {
    __shared__ int s[256];
    int tid = threadIdx.x, b = blockIdx.x;
    int base = b * 2048 + tid * 8;
    int v[8]; int t = 0;
#pragma unroll
    for (int i = 0; i < 8; ++i) { int idx = base + i; v[i] = (idx < N) ? cnt[idx] : 0; t += v[i]; }
    s[tid] = t; __syncthreads();
    for (int o = 1; o < 256; o <<= 1) {
        int u = (tid >= o) ? s[tid - o] : 0;
        __syncthreads();
        s[tid] += u;
        __syncthreads();
    }
    int run = s[tid] - t;
#pragma unroll
    for (int i = 0; i < 8; ++i) { int idx = base + i; if (idx < N) part[idx] = run; run += v[i]; }
    if (tid == 255) sums[b] = s[255];
}

__global__ void scan2_k(int* sums, int nb) {
    if (threadIdx.x == 0 && blockIdx.x == 0) {
        int run = 0;
        for (int i = 0; i < nb; ++i) { int t = sums[i]; sums[i] = run; run += t; }
    }
}

__global__ __launch_bounds__(256) void scan3_k(const int* __restrict__ part,
        const int* __restrict__ sums, int* __restrict__ ptr, int N, int E) {
    int i = blockIdx.x * 256 + threadIdx.x;
    if (i < N) ptr[i] = part[i] + sums[i >> 11];
    if (i == 0) ptr[N] = E;
}

__global__ __launch_bounds__(256) void scatter_k(const int* __restrict__ dst,
        const int* __restrict__ src, const int* __restrict__ ptr,
        int* __restrict__ fill, int* __restrict__ csr,
        int* __restrict__ rowid, int E) {
    int e = blockIdx.x * 256 + threadIdx.x;
    if (e < E) {
        int d = dst[e];
        int pos = ptr[d] + atomicAdd(&fill[d], 1);
        csr[pos] = src[e];
        rowid[pos] = d;
    }
}

// ---------------- edge weights, layer 1 ----------------
__global__ __launch_bounds__(256) void edgew1_k(const int* __restrict__ rowid,
        const int* __restrict__ csr, const float* __restrict__ ad,
        const float* __restrict__ as_, float4* __restrict__ w4, int E) {
    int i = blockIdx.x * 256 + threadIdx.x;
    if (i >= E) return;
    int d = rowid[i], s = csr[i];
    float e0 = lrelu_negexp(ad[d*3+0] + as_[s*3+0]);
    float e1 = lrelu_negexp(ad[d*3+1] + as_[s*3+1]);
    float e2 = lrelu_negexp(ad[d*3+2] + as_[s*3+2]);
    w4[i] = make_float4(e0, e1, e2, 0.f);
}

// ---------------- layer-1 aggregation: group-of-4 software pipeline ----------------
__global__ __launch_bounds__(256) void agg1_k(const float* __restrict__ h1,
        const float4* __restrict__ w4,
        const int* __restrict__ ptr, const int* __restrict__ csr,
        float* __restrict__ out1, int N) {
    int gt = blockIdx.x * 256 + threadIdx.x;
    int wid = gt >> 6, lane = gt & 63;
    if (wid >= N) return;
    int p0 = ptr[wid], p1 = ptr[wid + 1];
    float acc0 = 0, acc1 = 0, acc2 = 0, den0 = 0, den1 = 0, den2 = 0;
    int sSafe = csr[p0];

    int s0, s1, s2, s3;
    float4 w0, w1, w2, w3;
    float a0, b0, c0, a1f, b1f, c1f, a2f, b2f, c2f, a3f, b3f, c3f;

#define LDIDX(i, pos) { if ((pos) < p1) { s##i = csr[(pos)]; w##i = w4[(pos)]; } \
                        else { s##i = sSafe; w##i = make_float4(0.f,0.f,0.f,0.f); } }
#define LDROW(va, vb, vc, si) { const float* hp = h1 + (size_t)si * 192 + lane; \
                        va = hp[0]; vb = hp[64]; vc = hp[128]; }

    LDIDX(0, p0) LDIDX(1, p0+1) LDIDX(2, p0+2) LDIDX(3, p0+3)
    LDROW(a0, b0, c0, s0) LDROW(a1f, b1f, c1f, s1)
    LDROW(a2f, b2f, c2f, s2) LDROW(a3f, b3f, c3f, s3)

    for (int p = p0; p < p1; p += 4) {
        float ca0=a0, cb0=b0, cc0=c0, ca1=a1f, cb1=b1f, cc1=c1f;
        float ca2=a2f, cb2=b2f, cc2=c2f, ca3=a3f, cb3=b3f, cc3=c3f;
        float4 cw0=w0, cw1=w1, cw2=w2, cw3=w3;
        int np = p + 4;
        if (np < p1) {
            LDIDX(0, np) LDIDX(1, np+1) LDIDX(2, np+2) LDIDX(3, np+3)
            LDROW(a0, b0, c0, s0) LDROW(a1f, b1f, c1f, s1)
            LDROW(a2f, b2f, c2f, s2) LDROW(a3f, b3f, c3f, s3)
        }
        acc0 = fmaf(cw0.x, ca0, acc0); acc1 = fmaf(cw0.y, cb0, acc1); acc2 = fmaf(cw0.z, cc0, acc2);
        den0 += cw0.x; den1 += cw0.y; den2 += cw0.z;
        acc0 = fmaf(cw1.x, ca1, acc0); acc1 = fmaf(cw1.y, cb1, acc1); acc2 = fmaf(cw1.z, cc1, acc2);
        den0 += cw1.x; den1 += cw1.y; den2 += cw1.z;
        acc0 = fmaf(cw2.x, ca2, acc0); acc1 = fmaf(cw2.y, cb2, acc1); acc2 = fmaf(cw2.z, cc2, acc2);
        den0 += cw2.x; den1 += cw2.y; den2 += cw2.z;
        acc0 = fmaf(cw3.x, ca3, acc0); acc1 = fmaf(cw3.y, cb3, acc1); acc2 = fmaf(cw3.z, cc3, acc2);
        den0 += cw3.x; den1 += cw3.y; den2 += cw3.z;
    }
#undef LDIDX
#undef LDROW
    size_t ob = (size_t)wid * 192;
    out1[ob + lane]       = elu1(acc0 / (den0 + 1e-16f));
    out1[ob + 64 + lane]  = elu1(acc1 / (den1 + 1e-16f));
    out1[ob + 128 + lane] = elu1(acc2 / (den2 + 1e-16f));
}

// ---------------- GEMM2: h2[N,40] = out1[N,192] @ Wo[192,40] ----------------
__global__ __launch_bounds__(256) void gemm2_k(const float* __restrict__ X,
        const float* __restrict__ Wo, float* __restrict__ h2, int N) {
    __shared__ float Xs[32][193];
    __shared__ float Ws[192 * 40];
    const int tid = threadIdx.x;
    const int row0 = blockIdx.x * 32;
    for (int i = tid; i < 192 * 40; i += 256) Ws[i] = Wo[i];
    for (int i = tid; i < 32 * 48; i += 256) {
        int r = i / 48, c4 = (i % 48) * 4;
        int rr = row0 + r; if (rr >= N) rr = N - 1;
        float4 v = *(const float4*)(X + (size_t)rr * 192 + c4);
        Xs[r][c4+0] = v.x; Xs[r][c4+1] = v.y; Xs[r][c4+2] = v.z; Xs[r][c4+3] = v.w;
    }
    __syncthreads();
    int rsub = tid >> 3;
    int f0 = (tid & 7) * 5;
    float acc[5] = {0, 0, 0, 0, 0};
    for (int c = 0; c < 192; ++c) {
        float xv = Xs[rsub][c];
#pragma unroll
        for (int j = 0; j < 5; ++j) acc[j] = fmaf(xv, Ws[c*40 + f0 + j], acc[j]);
    }
    int r = row0 + rsub;
    if (r < N) {
#pragma unroll
        for (int j = 0; j < 5; ++j) h2[(size_t)r*40 + f0 + j] = acc[j];
    }
}

// ---------------- per-node logit dots, layer 2 ----------------
__global__ __launch_bounds__(256) void dots2_k(const float* __restrict__ h2,
        const float* __restrict__ a1o, const float* __restrict__ a2o,
        float* __restrict__ ad2, float* __restrict__ as2, int N) {
    int gt = blockIdx.x * 256 + threadIdx.x;
    int wid = gt >> 6, lane = gt & 63;
    if (wid >= N) return;
    float v = 0.f, w1 = 0.f, w2 = 0.f;
    if (lane < 40) { v = h2[(size_t)wid*40 + lane]; w1 = a1o[lane]; w2 = a2o[lane]; }
    float da = v * w1, db = v * w2;
#pragma unroll
    for (int o = 32; o > 0; o >>= 1) { da += __shfl_down(da, o, 64); db += __shfl_down(db, o, 64); }
    if (lane == 0) { ad2[wid] = da; as2[wid] = db; }
}

// ---------------- edge weights, layer 2 ----------------
__global__ __launch_bounds__(256) void edgew2_k(const int* __restrict__ rowid,
        const int* __restrict__ csr, const float* __restrict__ ad2,
        const float* __restrict__ as2, float* __restrict__ w2, int E) {
    int i = blockIdx.x * 256 + threadIdx.x;
    if (i >= E) return;
    w2[i] = lrelu_negexp(ad2[rowid[i]] + as2[csr[i]]);
}

// ---------------- layer-2 aggregation: group-of-4 software pipeline ----------------
__global__ __launch_bounds__(256) void agg2_k(const float* __restrict__ h2,
        const float* __restrict__ w2,
        const int* __restrict__ ptr, const int* __restrict__ csr,
        float* __restrict__ out, int N) {
    int gt = blockIdx.x * 256 + threadIdx.x;
    int wid = gt >> 6, lane = gt & 63;
    if (wid >= N) return;
    int p0 = ptr[wid], p1 = ptr[wid + 1];
    float acc = 0.f, den = 0.f;
    int sSafe = csr[p0];
    bool act = lane < 40;

    int s0, s1, s2, s3;
    float w0, w1, w2v, w3;
    float r0, r1, r2, r3;

#define LDIDX2(i, pos, wv) { if ((pos) < p1) { s##i = csr[(pos)]; wv = w2[(pos)]; } \
                             else { s##i = sSafe; wv = 0.f; } }
#define LDROW2(rv, si) { rv = act ? h2[(size_t)si * 40 + lane] : 0.f; }

    LDIDX2(0, p0, w0) LDIDX2(1, p0+1, w1) LDIDX2(2, p0+2, w2v) LDIDX2(3, p0+3, w3)
    LDROW2(r0, s0) LDROW2(r1, s1) LDROW2(r2, s2) LDROW2(r3, s3)

    for (int p = p0; p < p1; p += 4) {
        float cr0=r0, cr1=r1, cr2=r2, cr3=r3;
        float cw0=w0, cw1=w1, cw2=w2v, cw3=w3;
        int np = p + 4;
        if (np < p1) {
            LDIDX2(0, np, w0) LDIDX2(1, np+1, w1) LDIDX2(2, np+2, w2v) LDIDX2(3, np+3, w3)
            LDROW2(r0, s0) LDROW2(r1, s1) LDROW2(r2, s2) LDROW2(r3, s3)
        }
        acc = fmaf(cw0, cr0, acc); den += cw0;
        acc = fmaf(cw1, cr1, acc); den += cw1;
        acc = fmaf(cw2, cr2, acc); den += cw2;
        acc = fmaf(cw3, cr3, acc); den += cw3;
    }
#undef LDIDX2
#undef LDROW2
    float o = elu1(acc / (den + 1e-16f));
    if (act) out[(size_t)wid*40 + lane] = o;
}

extern "C" void kernel_launch(void* const* d_in, const int* in_sizes, int n_in,
                              void* d_out, int out_size, void* d_ws, size_t ws_size,
                              hipStream_t stream) {
    const float* x   = (const float*)d_in[0];
    const int*   ei  = (const int*)d_in[1];
    const float* W   = (const float*)d_in[2];
    const float* a1  = (const float*)d_in[3];
    const float* a2  = (const float*)d_in[4];
    const float* Wo  = (const float*)d_in[5];
    const float* a1o = (const float*)d_in[6];
    const float* a2o = (const float*)d_in[7];
    const int N = in_sizes[0] / NFEAT;
    const int E = in_sizes[1] / 2;
    const int* dst = ei;
    const int* src = ei + E;

    char* base = (char*)d_ws;
    size_t off = 0;
    auto alloc = [&](size_t bytes) { void* p = base + off; off += (bytes + 255) & ~(size_t)255; return p; };
    float*  h1    = (float*)alloc((size_t)N * 192 * 4);
    float*  out1  = (float*)alloc((size_t)N * 192 * 4);
    int*    csr   = (int*)alloc((size_t)E * 4);
    int*    rowid = (int*)alloc((size_t)E * 4);
    float4* w4    = (float4*)alloc((size_t)E * 16);
    int*    ptr   = (int*)alloc((size_t)(N + 1) * 4);
    int*    cnt   = (int*)alloc((size_t)N * 4);
    int*    part  = (int*)alloc((size_t)N * 4);
    int*    sums  = (int*)alloc(1024);
    float*  ad1   = (float*)alloc((size_t)N * 3 * 4);
    float*  as1   = (float*)alloc((size_t)N * 3 * 4);
    unsigned short* wthi = (unsigned short*)alloc((size_t)NHEADS * NHID * NFEAT * 2);
    unsigned short* wtlo = (unsigned short*)alloc((size_t)NHEADS * NHID * NFEAT * 2);
    // aliases: xhi lives in out1 (N*256*2 = 51.2MB <= 76.8MB, dead until agg1 writes out1);
    //          xlo lives in w4  (51.2MB <= 52.8MB, dead until edgew1 writes w4)
    unsigned short* xhi = (unsigned short*)out1;
    unsigned short* xlo = (unsigned short*)w4;
    // layer-2 buffers alias dead regions of h1
    float* h2  = h1;
    float* ad2 = h1 + (size_t)N * 40;
    float* as2 = ad2 + N;
    float* w2  = (float*)w4;

    hipMemsetAsync(cnt, 0, (size_t)N * 4, stream);

    long n4 = (long)N * NFEAT / 4;
    cvt_x_k<<<(int)((n4 + 255) / 256), 256, 0, stream>>>(x, xhi, xlo, n4);
    cvt_w_k<<<(NHEADS * NHID * NFEAT + 255) / 256, 256, 0, stream>>>(W, wthi, wtlo);
    gemm1_mfma_k<<<(N + 127) / 128, 256, 0, stream>>>(xhi, xlo, wthi, wtlo, h1, N);

    hist_k<<<(E + 255) / 256, 256, 0, stream>>>(dst, cnt, E);
    int nb = (N + 2047) / 2048;
    scan1_k<<<nb, 256, 0, stream>>>(cnt, part, sums, N);
    scan2_k<<<1, 64, 0, stream>>>(sums, nb);
    scan3_k<<<(N + 255) / 256, 256, 0, stream>>>(part, sums, ptr, N, E);
    hipMemsetAsync(cnt, 0, (size_t)N * 4, stream);
    scatter_k<<<(E + 255) / 256, 256, 0, stream>>>(dst, src, ptr, cnt, csr, rowid, E);

    dots1_k<<<(N + 3) / 4, 256, 0, stream>>>(h1, a1, a2, ad1, as1, N);
    edgew1_k<<<(E + 255) / 256, 256, 0, stream>>>(rowid, csr, ad1, as1, w4, E);
    agg1_k<<<(N + 3) / 4, 256, 0, stream>>>(h1, w4, ptr, csr, out1, N);

    gemm2_k<<<(N + 31) / 32, 256, 0, stream>>>(out1, Wo, h2, N);
    dots2_k<<<(N + 3) / 4, 256, 0, stream>>>(h2, a1o, a2o, ad2, as2, N);
    edgew2_k<<<(E + 255) / 256, 256, 0, stream>>>(rowid, csr, ad2, as2, w2, E);
    agg2_k<<<(N + 3) / 4, 256, 0, stream>>>(h2, w2, ptr, csr, (float*)d_out, N);
}

// Round 4
// 1231.321 us; speedup vs baseline: 1.1347x; 1.0067x over previous
//
#include <hip/hip_runtime.h>

#define ALPHA 0.2f
#define NFEAT 256
#define NHID 64
#define NHEADS 3
#define NCLASS 40

typedef short short8 __attribute__((ext_vector_type(8)));
typedef float float4v __attribute__((ext_vector_type(4)));

__device__ __forceinline__ float lrelu_negexp(float x) {
    float l = x > 0.f ? x : ALPHA * x;
    return __expf(-l);
}
__device__ __forceinline__ float elu1(float x) {
    return x > 0.f ? x : (__expf(x) - 1.f);
}
__device__ __forceinline__ unsigned short f2bf(float f) {
    unsigned int u = __float_as_uint(f);
    unsigned int r = (u + 0x7FFFu + ((u >> 16) & 1u)) >> 16;   // RN-even
    return (unsigned short)r;
}
__device__ __forceinline__ float bf2f(unsigned short h) {
    return __uint_as_float(((unsigned int)h) << 16);
}

// ---------------- convert x -> bf16 hi/lo split ----------------
__global__ __launch_bounds__(256) void cvt_x_k(const float* __restrict__ x,
        unsigned short* __restrict__ xhi, unsigned short* __restrict__ xlo, long n4) {
    long i = (long)blockIdx.x * 256 + threadIdx.x;
    if (i >= n4) return;
    float4 v = ((const float4*)x)[i];
    ushort4 hi, lo;
    hi.x = f2bf(v.x); lo.x = f2bf(v.x - bf2f(hi.x));
    hi.y = f2bf(v.y); lo.y = f2bf(v.y - bf2f(hi.y));
    hi.z = f2bf(v.z); lo.z = f2bf(v.z - bf2f(hi.z));
    hi.w = f2bf(v.w); lo.w = f2bf(v.w - bf2f(hi.w));
    ((ushort4*)xhi)[i] = hi;
    ((ushort4*)xlo)[i] = lo;
}

// ---------------- convert + transpose W: [3][256][64] -> Wt[192][256] hi/lo ----------------
__global__ __launch_bounds__(256) void cvt_w_k(const float* __restrict__ W,
        unsigned short* __restrict__ wthi, unsigned short* __restrict__ wtlo) {
    int i = blockIdx.x * 256 + threadIdx.x;   // over 3*64*256
    if (i >= NHEADS * NHID * NFEAT) return;
    int k = i & 255, nc = (i >> 8) & 63, head = i >> 14;
    float v = W[(size_t)head * NFEAT * NHID + (size_t)k * NHID + nc];
    unsigned short hi = f2bf(v);
    unsigned short lo = f2bf(v - bf2f(hi));
    wthi[i] = hi;   // layout: [(head*64+nc)][k], k contiguous
    wtlo[i] = lo;
}

// ---------------- GEMM1 via split-bf16 MFMA ----------------
// block: 128 rows x 192 cols, 4 waves in 2x2 grid (wave tile 64M x 96N), BK=32
__global__ __launch_bounds__(256) void gemm1_mfma_k(
        const unsigned short* __restrict__ xhi, const unsigned short* __restrict__ xlo,
        const unsigned short* __restrict__ wthi, const unsigned short* __restrict__ wtlo,
        float* __restrict__ h1, int N) {
    __shared__ unsigned short Ah[128 * 40];   // padded stride 40 shorts (80 B)
    __shared__ unsigned short Al[128 * 40];
    __shared__ unsigned short Bh[192 * 40];
    __shared__ unsigned short Bl[192 * 40];
    const int tid = threadIdx.x;
    const int wave = tid >> 6, lane = tid & 63;
    const int quad = lane >> 4, l16 = lane & 15;
    const int row0 = blockIdx.x * 128;
    const int wm = (wave >> 1) * 64;
    const int wn = (wave & 1) * 96;

    float4v acc[4][6];
#pragma unroll
    for (int s = 0; s < 4; ++s)
#pragma unroll
        for (int t = 0; t < 6; ++t)
            acc[s][t] = (float4v){0.f, 0.f, 0.f, 0.f};

    for (int kc = 0; kc < NFEAT; kc += 32) {
#pragma unroll
        for (int rr = 0; rr < 2; ++rr) {
            int idx = rr * 256 + tid;
            int r = idx >> 2, kq = (idx & 3) * 8;
            int gr = row0 + r; if (gr >= N) gr = N - 1;
            size_t g = (size_t)gr * NFEAT + kc + kq;
            *(int4*)&Ah[r * 40 + kq] = *(const int4*)(xhi + g);
            *(int4*)&Al[r * 40 + kq] = *(const int4*)(xlo + g);
        }
#pragma unroll
        for (int rr = 0; rr < 3; ++rr) {
            int idx = rr * 256 + tid;
            int r = idx >> 2, kq = (idx & 3) * 8;
            size_t g = (size_t)r * NFEAT + kc + kq;
            *(int4*)&Bh[r * 40 + kq] = *(const int4*)(wthi + g);
            *(int4*)&Bl[r * 40 + kq] = *(const int4*)(wtlo + g);
        }
        __syncthreads();

        short8 ah[4], al[4];
#pragma unroll
        for (int s = 0; s < 4; ++s) {
            int m = wm + s * 16 + l16;
            ah[s] = *(const short8*)&Ah[m * 40 + quad * 8];
            al[s] = *(const short8*)&Al[m * 40 + quad * 8];
        }
#pragma unroll
        for (int t = 0; t < 6; ++t) {
            int n = wn + t * 16 + l16;
            short8 bh = *(const short8*)&Bh[n * 40 + quad * 8];
            short8 bl = *(const short8*)&Bl[n * 40 + quad * 8];
#pragma unroll
            for (int s = 0; s < 4; ++s) {
                acc[s][t] = __builtin_amdgcn_mfma_f32_16x16x32_bf16(ah[s], bh, acc[s][t], 0, 0, 0);
                acc[s][t] = __builtin_amdgcn_mfma_f32_16x16x32_bf16(ah[s], bl, acc[s][t], 0, 0, 0);
                acc[s][t] = __builtin_amdgcn_mfma_f32_16x16x32_bf16(al[s], bh, acc[s][t], 0, 0, 0);
            }
        }
        __syncthreads();
    }
#pragma unroll
    for (int s = 0; s < 4; ++s) {
#pragma unroll
        for (int r = 0; r < 4; ++r) {
            int grow = row0 + wm + s * 16 + quad * 4 + r;
            if (grow < N) {
#pragma unroll
                for (int t = 0; t < 6; ++t)
                    h1[(size_t)grow * 192 + wn + t * 16 + l16] = acc[s][t][r];
            }
        }
    }
}

// ---------------- per-node logit dots, layer 1 ----------------
__global__ __launch_bounds__(256) void dots1_k(const float* __restrict__ h1,
        const float* __restrict__ a1, const float* __restrict__ a2,
        float* __restrict__ ad, float* __restrict__ as_, int N) {
    int gt = blockIdx.x * 256 + threadIdx.x;
    int wid = gt >> 6, lane = gt & 63;
    if (wid >= N) return;
    const float* hr = h1 + (size_t)wid * 192;
#pragma unroll
    for (int k = 0; k < 3; ++k) {
        float v = hr[k*64 + lane];
        float da = v * a1[k*64 + lane];
        float db = v * a2[k*64 + lane];
#pragma unroll
        for (int o = 32; o > 0; o >>= 1) {
            da += __shfl_down(da, o, 64);
            db += __shfl_down(db, o, 64);
        }
        if (lane == 0) { ad[wid*3+k] = da; as_[wid*3+k] = db; }
    }
}

// ---------------- CSR build ----------------
__global__ __launch_bounds__(256) void hist_k(const int* __restrict__ dst,
        int* __restrict__ cnt, int E) {
    int e = blockIdx.x * 256 + threadIdx.x;
    if (e < E) atomicAdd(&cnt[dst[e]], 1);
}

__global__ __launch_bounds__(256) void scan1_k(const int* __restrict__ cnt,
        int* __restrict__ part, int* __restrict__ sums, int N) {
    __shared__ int s[256];
    int tid = threadIdx.x, b = blockIdx.x;
    int base = b * 2048 + tid * 8;
    int v[8]; int t = 0;
#pragma unroll
    for (int i = 0; i < 8; ++i) { int idx = base + i; v[i] = (idx < N) ? cnt[idx] : 0; t += v[i]; }
    s[tid] = t; __syncthreads();
    for (int o = 1; o < 256; o <<= 1) {
        int u = (tid >= o) ? s[tid - o] : 0;
        __syncthreads();
        s[tid] += u;
        __syncthreads();
    }
    int run = s[tid] - t;
#pragma unroll
    for (int i = 0; i < 8; ++i) { int idx = base + i; if (idx < N) part[idx] = run; run += v[i]; }
    if (tid == 255) sums[b] = s[255];
}

__global__ void scan2_k(int* sums, int nb) {
    if (threadIdx.x == 0 && blockIdx.x == 0) {
        int run = 0;
        for (int i = 0; i < nb; ++i) { int t = sums[i]; sums[i] = run; run += t; }
    }
}

__global__ __launch_bounds__(256) void scan3_k(const int* __restrict__ part,
        const int* __restrict__ sums, int* __restrict__ ptr, int N, int E) {
    int i = blockIdx.x * 256 + threadIdx.x;
    if (i < N) ptr[i] = part[i] + sums[i >> 11];
    if (i == 0) ptr[N] = E;
}

__global__ __launch_bounds__(256) void scatter_k(const int* __restrict__ dst,
        const int* __restrict__ src, const int* __restrict__ ptr,
        int* __restrict__ fill, int* __restrict__ csr,
        int* __restrict__ rowid, int E) {
    int e = blockIdx.x * 256 + threadIdx.x;
    if (e < E) {
        int d = dst[e];
        int pos = ptr[d] + atomicAdd(&fill[d], 1);
        csr[pos] = src[e];
        rowid[pos] = d;
    }
}

// ---------------- edge weights, layer 1: per-head scalar streams wE[h*E + i] ----------------
__global__ __launch_bounds__(256) void edgew1_k(const int* __restrict__ rowid,
        const int* __restrict__ csr, const float* __restrict__ ad,
        const float* __restrict__ as_, float* __restrict__ wE, int E) {
    int i = blockIdx.x * 256 + threadIdx.x;
    if (i >= E) return;
    int d = rowid[i], s = csr[i];
    wE[i]         = lrelu_negexp(ad[d*3+0] + as_[s*3+0]);
    wE[E + i]     = lrelu_negexp(ad[d*3+1] + as_[s*3+1]);
    wE[2*E + i]   = lrelu_negexp(ad[d*3+2] + as_[s*3+2]);
}

// ---------------- layer-1 aggregation, ONE HEAD: wave per node, lane = feature ----------------
// Working set = 25.6 MB head slice of h1 -> L3-resident.
__global__ __launch_bounds__(256) void agg1h_k(const float* __restrict__ h1,
        const float* __restrict__ wE,
        const int* __restrict__ ptr, const int* __restrict__ csr,
        float* __restrict__ out1, int head, int N) {
    int gt = blockIdx.x * 256 + threadIdx.x;
    int wid = gt >> 6, lane = gt & 63;
    if (wid >= N) return;
    int p0 = ptr[wid], p1 = ptr[wid + 1];
    const float* hbase = h1 + head * 64 + lane;
    float acc = 0.f, den = 0.f;
    int sSafe = csr[p0];

#define G 8
    int s[G]; float w[G], v[G];
#define LD1(i, pos) { if ((pos) < p1) { s[i] = csr[(pos)]; w[i] = wE[(pos)]; } \
                      else { s[i] = sSafe; w[i] = 0.f; } }
#pragma unroll
    for (int i = 0; i < G; ++i) LD1(i, p0 + i)
#pragma unroll
    for (int i = 0; i < G; ++i) v[i] = hbase[(size_t)s[i] * 192];

    for (int p = p0; p < p1; p += G) {
        float cv[G], cw[G];
#pragma unroll
        for (int i = 0; i < G; ++i) { cv[i] = v[i]; cw[i] = w[i]; }
        int np = p + G;
        if (np < p1) {
#pragma unroll
            for (int i = 0; i < G; ++i) LD1(i, np + i)
#pragma unroll
            for (int i = 0; i < G; ++i) v[i] = hbase[(size_t)s[i] * 192];
        }
#pragma unroll
        for (int i = 0; i < G; ++i) { acc = fmaf(cw[i], cv[i], acc); den += cw[i]; }
    }
#undef LD1
#undef G
    out1[(size_t)wid * 192 + head * 64 + lane] = elu1(acc / (den + 1e-16f));
}

// ---------------- GEMM2: h2[N,40] = out1[N,192] @ Wo[192,40] ----------------
__global__ __launch_bounds__(256) void gemm2_k(const float* __restrict__ X,
        const float* __restrict__ Wo, float* __restrict__ h2, int N) {
    __shared__ float Xs[32][193];
    __shared__ float Ws[192 * 40];
    const int tid = threadIdx.x;
    const int row0 = blockIdx.x * 32;
    for (int i = tid; i < 192 * 40; i += 256) Ws[i] = Wo[i];
    for (int i = tid; i < 32 * 48; i += 256) {
        int r = i / 48, c4 = (i % 48) * 4;
        int rr = row0 + r; if (rr >= N) rr = N - 1;
        float4 v = *(const float4*)(X + (size_t)rr * 192 + c4);
        Xs[r][c4+0] = v.x; Xs[r][c4+1] = v.y; Xs[r][c4+2] = v.z; Xs[r][c4+3] = v.w;
    }
    __syncthreads();
    int rsub = tid >> 3;
    int f0 = (tid & 7) * 5;
    float acc[5] = {0, 0, 0, 0, 0};
    for (int c = 0; c < 192; ++c) {
        float xv = Xs[rsub][c];
#pragma unroll
        for (int j = 0; j < 5; ++j) acc[j] = fmaf(xv, Ws[c*40 + f0 + j], acc[j]);
    }
    int r = row0 + rsub;
    if (r < N) {
#pragma unroll
        for (int j = 0; j < 5; ++j) h2[(size_t)r*40 + f0 + j] = acc[j];
    }
}

// ---------------- per-node logit dots, layer 2 ----------------
__global__ __launch_bounds__(256) void dots2_k(const float* __restrict__ h2,
        const float* __restrict__ a1o, const float* __restrict__ a2o,
        float* __restrict__ ad2, float* __restrict__ as2, int N) {
    int gt = blockIdx.x * 256 + threadIdx.x;
    int wid = gt >> 6, lane = gt & 63;
    if (wid >= N) return;
    float v = 0.f, w1 = 0.f, w2 = 0.f;
    if (lane < 40) { v = h2[(size_t)wid*40 + lane]; w1 = a1o[lane]; w2 = a2o[lane]; }
    float da = v * w1, db = v * w2;
#pragma unroll
    for (int o = 32; o > 0; o >>= 1) { da += __shfl_down(da, o, 64); db += __shfl_down(db, o, 64); }
    if (lane == 0) { ad2[wid] = da; as2[wid] = db; }
}

// ---------------- edge weights, layer 2 ----------------
__global__ __launch_bounds__(256) void edgew2_k(const int* __restrict__ rowid,
        const int* __restrict__ csr, const float* __restrict__ ad2,
        const float* __restrict__ as2, float* __restrict__ w2, int E) {
    int i = blockIdx.x * 256 + threadIdx.x;
    if (i >= E) return;
    w2[i] = lrelu_negexp(ad2[rowid[i]] + as2[csr[i]]);
}

// ---------------- layer-2 aggregation: group-of-4 software pipeline ----------------
__global__ __launch_bounds__(256) void agg2_k(const float* __restrict__ h2,
        const float* __restrict__ w2,
        const int* __restrict__ ptr, const int* __restrict__ csr,
        float* __restrict__ out, int N) {
    int gt = blockIdx.x * 256 + threadIdx.x;
    int wid = gt >> 6, lane = gt & 63;
    if (wid >= N) return;
    int p0 = ptr[wid], p1 = ptr[wid + 1];
    float acc = 0.f, den = 0.f;
    int sSafe = csr[p0];
    bool act = lane < 40;

    int s0, s1, s2, s3;
    float w0, w1, w2v, w3;
    float r0, r1, r2, r3;

#define LDIDX2(i, pos, wv) { if ((pos) < p1) { s##i = csr[(pos)]; wv = w2[(pos)]; } \
                             else { s##i = sSafe; wv = 0.f; } }
#define LDROW2(rv, si) { rv = act ? h2[(size_t)si * 40 + lane] : 0.f; }

    LDIDX2(0, p0, w0) LDIDX2(1, p0+1, w1) LDIDX2(2, p0+2, w2v) LDIDX2(3, p0+3, w3)
    LDROW2(r0, s0) LDROW2(r1, s1) LDROW2(r2, s2) LDROW2(r3, s3)

    for (int p = p0; p < p1; p += 4) {
        float cr0=r0, cr1=r1, cr2=r2, cr3=r3;
        float cw0=w0, cw1=w1, cw2=w2v, cw3=w3;
        int np = p + 4;
        if (np < p1) {
            LDIDX2(0, np, w0) LDIDX2(1, np+1, w1) LDIDX2(2, np+2, w2v) LDIDX2(3, np+3, w3)
            LDROW2(r0, s0) LDROW2(r1, s1) LDROW2(r2, s2) LDROW2(r3, s3)
        }
        acc = fmaf(cw0, cr0, acc); den += cw0;
        acc = fmaf(cw1, cr1, acc); den += cw1;
        acc = fmaf(cw2, cr2, acc); den += cw2;
        acc = fmaf(cw3, cr3, acc); den += cw3;
    }
#undef LDIDX2
#undef LDROW2
    float o = elu1(acc / (den + 1e-16f));
    if (act) out[(size_t)wid*40 + lane] = o;
}

extern "C" void kernel_launch(void* const* d_in, const int* in_sizes, int n_in,
                              void* d_out, int out_size, void* d_ws, size_t ws_size,
                              hipStream_t stream) {
    const float* x   = (const float*)d_in[0];
    const int*   ei  = (const int*)d_in[1];
    const float* W   = (const float*)d_in[2];
    const float* a1  = (const float*)d_in[3];
    const float* a2  = (const float*)d_in[4];
    const float* Wo  = (const float*)d_in[5];
    const float* a1o = (const float*)d_in[6];
    const float* a2o = (const float*)d_in[7];
    const int N = in_sizes[0] / NFEAT;
    const int E = in_sizes[1] / 2;
    const int* dst = ei;
    const int* src = ei + E;

    char* base = (char*)d_ws;
    size_t off = 0;
    auto alloc = [&](size_t bytes) { void* p = base + off; off += (bytes + 255) & ~(size_t)255; return p; };
    float*  h1    = (float*)alloc((size_t)N * 192 * 4);
    float*  out1  = (float*)alloc((size_t)N * 192 * 4);
    int*    csr   = (int*)alloc((size_t)E * 4);
    int*    rowid = (int*)alloc((size_t)E * 4);
    float*  wEbuf = (float*)alloc((size_t)E * 16);      // holds wE[3*E] (and xlo before edgew1)
    int*    ptr   = (int*)alloc((size_t)(N + 1) * 4);
    int*    cnt   = (int*)alloc((size_t)N * 4);
    int*    part  = (int*)alloc((size_t)N * 4);
    int*    sums  = (int*)alloc(1024);
    float*  ad1   = (float*)alloc((size_t)N * 3 * 4);
    float*  as1   = (float*)alloc((size_t)N * 3 * 4);
    unsigned short* wthi = (unsigned short*)alloc((size_t)NHEADS * NHID * NFEAT * 2);
    unsigned short* wtlo = (unsigned short*)alloc((size_t)NHEADS * NHID * NFEAT * 2);
    // aliases: xhi lives in out1 (51.2MB <= 76.8MB, dead until agg1h writes out1);
    //          xlo lives in wEbuf (51.2MB <= 52.8MB, dead until edgew1 writes wE)
    unsigned short* xhi = (unsigned short*)out1;
    unsigned short* xlo = (unsigned short*)wEbuf;
    // layer-2 buffers alias dead regions of h1
    float* h2  = h1;
    float* ad2 = h1 + (size_t)N * 40;
    float* as2 = ad2 + N;
    float* w2  = wEbuf;

    hipMemsetAsync(cnt, 0, (size_t)N * 4, stream);

    long n4 = (long)N * NFEAT / 4;
    cvt_x_k<<<(int)((n4 + 255) / 256), 256, 0, stream>>>(x, xhi, xlo, n4);
    cvt_w_k<<<(NHEADS * NHID * NFEAT + 255) / 256, 256, 0, stream>>>(W, wthi, wtlo);
    gemm1_mfma_k<<<(N + 127) / 128, 256, 0, stream>>>(xhi, xlo, wthi, wtlo, h1, N);

    hist_k<<<(E + 255) / 256, 256, 0, stream>>>(dst, cnt, E);
    int nb = (N + 2047) / 2048;
    scan1_k<<<nb, 256, 0, stream>>>(cnt, part, sums, N);
    scan2_k<<<1, 64, 0, stream>>>(sums, nb);
    scan3_k<<<(N + 255) / 256, 256, 0, stream>>>(part, sums, ptr, N, E);
    hipMemsetAsync(cnt, 0, (size_t)N * 4, stream);
    scatter_k<<<(E + 255) / 256, 256, 0, stream>>>(dst, src, ptr, cnt, csr, rowid, E);

    dots1_k<<<(N + 3) / 4, 256, 0, stream>>>(h1, a1, a2, ad1, as1, N);
    edgew1_k<<<(E + 255) / 256, 256, 0, stream>>>(rowid, csr, ad1, as1, wEbuf, E);
    for (int head = 0; head < NHEADS; ++head)
        agg1h_k<<<(N + 3) / 4, 256, 0, stream>>>(h1, wEbuf + (size_t)head * E,
                                                 ptr, csr, out1, head, N);

    gemm2_k<<<(N + 31) / 32, 256, 0, stream>>>(out1, Wo, h2, N);
    dots2_k<<<(N + 3) / 4, 256, 0, stream>>>(h2, a1o, a2o, ad2, as2, N);
    edgew2_k<<<(E + 255) / 256, 256, 0, stream>>>(rowid, csr, ad2, as2, w2, E);
    agg2_k<<<(N + 3) / 4, 256, 0, stream>>>(h2, w2, ptr, csr, (float*)d_out, N);
}

// Round 5
// 1161.706 us; speedup vs baseline: 1.2027x; 1.0599x over previous
//
#include <hip/hip_runtime.h>

#define ALPHA 0.2f
#define NFEAT 256
#define NHID 64
#define NHEADS 3
#define NCLASS 40

typedef short short8 __attribute__((ext_vector_type(8)));
typedef float float4v __attribute__((ext_vector_type(4)));
typedef _Float16 half4_t __attribute__((ext_vector_type(4)));

__device__ __forceinline__ float lrelu_negexp(float x) {
    float l = x > 0.f ? x : ALPHA * x;
    return __expf(-l);
}
__device__ __forceinline__ float elu1(float x) {
    return x > 0.f ? x : (__expf(x) - 1.f);
}
__device__ __forceinline__ unsigned short f2bf(float f) {
    unsigned int u = __float_as_uint(f);
    unsigned int r = (u + 0x7FFFu + ((u >> 16) & 1u)) >> 16;   // RN-even
    return (unsigned short)r;
}
__device__ __forceinline__ float bf2f(unsigned short h) {
    return __uint_as_float(((unsigned int)h) << 16);
}

// ---------------- convert x -> bf16 hi/lo split ----------------
__global__ __launch_bounds__(256) void cvt_x_k(const float* __restrict__ x,
        unsigned short* __restrict__ xhi, unsigned short* __restrict__ xlo, long n4) {
    long i = (long)blockIdx.x * 256 + threadIdx.x;
    if (i >= n4) return;
    float4 v = ((const float4*)x)[i];
    ushort4 hi, lo;
    hi.x = f2bf(v.x); lo.x = f2bf(v.x - bf2f(hi.x));
    hi.y = f2bf(v.y); lo.y = f2bf(v.y - bf2f(hi.y));
    hi.z = f2bf(v.z); lo.z = f2bf(v.z - bf2f(hi.z));
    hi.w = f2bf(v.w); lo.w = f2bf(v.w - bf2f(hi.w));
    ((ushort4*)xhi)[i] = hi;
    ((ushort4*)xlo)[i] = lo;
}

// ---------------- convert + transpose W: [3][256][64] -> Wt[192][256] hi/lo ----------------
__global__ __launch_bounds__(256) void cvt_w_k(const float* __restrict__ W,
        unsigned short* __restrict__ wthi, unsigned short* __restrict__ wtlo) {
    int i = blockIdx.x * 256 + threadIdx.x;   // over 3*64*256
    if (i >= NHEADS * NHID * NFEAT) return;
    int k = i & 255, nc = (i >> 8) & 63, head = i >> 14;
    float v = W[(size_t)head * NFEAT * NHID + (size_t)k * NHID + nc];
    unsigned short hi = f2bf(v);
    unsigned short lo = f2bf(v - bf2f(hi));
    wthi[i] = hi;   // layout: [(head*64+nc)][k], k contiguous
    wtlo[i] = lo;
}

// ---------------- GEMM1 via split-bf16 MFMA; epilogue writes fp16 h1h ----------------
__global__ __launch_bounds__(256) void gemm1_mfma_k(
        const unsigned short* __restrict__ xhi, const unsigned short* __restrict__ xlo,
        const unsigned short* __restrict__ wthi, const unsigned short* __restrict__ wtlo,
        _Float16* __restrict__ h1h, int N) {
    __shared__ unsigned short Ah[128 * 40];
    __shared__ unsigned short Al[128 * 40];
    __shared__ unsigned short Bh[192 * 40];
    __shared__ unsigned short Bl[192 * 40];
    const int tid = threadIdx.x;
    const int wave = tid >> 6, lane = tid & 63;
    const int quad = lane >> 4, l16 = lane & 15;
    const int row0 = blockIdx.x * 128;
    const int wm = (wave >> 1) * 64;
    const int wn = (wave & 1) * 96;

    float4v acc[4][6];
#pragma unroll
    for (int s = 0; s < 4; ++s)
#pragma unroll
        for (int t = 0; t < 6; ++t)
            acc[s][t] = (float4v){0.f, 0.f, 0.f, 0.f};

    for (int kc = 0; kc < NFEAT; kc += 32) {
#pragma unroll
        for (int rr = 0; rr < 2; ++rr) {
            int idx = rr * 256 + tid;
            int r = idx >> 2, kq = (idx & 3) * 8;
            int gr = row0 + r; if (gr >= N) gr = N - 1;
            size_t g = (size_t)gr * NFEAT + kc + kq;
            *(int4*)&Ah[r * 40 + kq] = *(const int4*)(xhi + g);
            *(int4*)&Al[r * 40 + kq] = *(const int4*)(xlo + g);
        }
#pragma unroll
        for (int rr = 0; rr < 3; ++rr) {
            int idx = rr * 256 + tid;
            int r = idx >> 2, kq = (idx & 3) * 8;
            size_t g = (size_t)r * NFEAT + kc + kq;
            *(int4*)&Bh[r * 40 + kq] = *(const int4*)(wthi + g);
            *(int4*)&Bl[r * 40 + kq] = *(const int4*)(wtlo + g);
        }
        __syncthreads();

        short8 ah[4], al[4];
#pragma unroll
        for (int s = 0; s < 4; ++s) {
            int m = wm + s * 16 + l16;
            ah[s] = *(const short8*)&Ah[m * 40 + quad * 8];
            al[s] = *(const short8*)&Al[m * 40 + quad * 8];
        }
#pragma unroll
        for (int t = 0; t < 6; ++t) {
            int n = wn + t * 16 + l16;
            short8 bh = *(const short8*)&Bh[n * 40 + quad * 8];
            short8 bl = *(const short8*)&Bl[n * 40 + quad * 8];
#pragma unroll
            for (int s = 0; s < 4; ++s) {
                acc[s][t] = __builtin_amdgcn_mfma_f32_16x16x32_bf16(ah[s], bh, acc[s][t], 0, 0, 0);
                acc[s][t] = __builtin_amdgcn_mfma_f32_16x16x32_bf16(ah[s], bl, acc[s][t], 0, 0, 0);
                acc[s][t] = __builtin_amdgcn_mfma_f32_16x16x32_bf16(al[s], bh, acc[s][t], 0, 0, 0);
            }
        }
        __syncthreads();
    }
#pragma unroll
    for (int s = 0; s < 4; ++s) {
#pragma unroll
        for (int r = 0; r < 4; ++r) {
            int grow = row0 + wm + s * 16 + quad * 4 + r;
            if (grow < N) {
#pragma unroll
                for (int t = 0; t < 6; ++t)
                    h1h[(size_t)grow * 192 + wn + t * 16 + l16] = (_Float16)acc[s][t][r];
            }
        }
    }
}

// ---------------- per-node logit dots, layer 1 (fp16 h1) ----------------
__global__ __launch_bounds__(256) void dots1_k(const _Float16* __restrict__ h1h,
        const float* __restrict__ a1, const float* __restrict__ a2,
        float* __restrict__ ad, float* __restrict__ as_, int N) {
    int gt = blockIdx.x * 256 + threadIdx.x;
    int wid = gt >> 6, lane = gt & 63;
    if (wid >= N) return;
    const _Float16* hr = h1h + (size_t)wid * 192;
#pragma unroll
    for (int k = 0; k < 3; ++k) {
        float v = (float)hr[k*64 + lane];
        float da = v * a1[k*64 + lane];
        float db = v * a2[k*64 + lane];
#pragma unroll
        for (int o = 32; o > 0; o >>= 1) {
            da += __shfl_down(da, o, 64);
            db += __shfl_down(db, o, 64);
        }
        if (lane == 0) { ad[wid*3+k] = da; as_[wid*3+k] = db; }
    }
}

// ---------------- CSR build: hist records per-edge rank ----------------
__global__ __launch_bounds__(256) void hist_k(const int* __restrict__ dst,
        int* __restrict__ cnt, int* __restrict__ rank, int E) {
    int e = blockIdx.x * 256 + threadIdx.x;
    if (e < E) rank[e] = atomicAdd(&cnt[dst[e]], 1);
}

__global__ __launch_bounds__(256) void scan1_k(const int* __restrict__ cnt,
        int* __restrict__ part, int* __restrict__ sums, int N) {
    __shared__ int s[256];
    int tid = threadIdx.x, b = blockIdx.x;
    int base = b * 2048 + tid * 8;
    int v[8]; int t = 0;
#pragma unroll
    for (int i = 0; i < 8; ++i) { int idx = base + i; v[i] = (idx < N) ? cnt[idx] : 0; t += v[i]; }
    s[tid] = t; __syncthreads();
    for (int o = 1; o < 256; o <<= 1) {
        int u = (tid >= o) ? s[tid - o] : 0;
        __syncthreads();
        s[tid] += u;
        __syncthreads();
    }
    int run = s[tid] - t;
#pragma unroll
    for (int i = 0; i < 8; ++i) { int idx = base + i; if (idx < N) part[idx] = run; run += v[i]; }
    if (tid == 255) sums[b] = s[255];
}

__global__ void scan2_k(int* sums, int nb) {
    if (threadIdx.x == 0 && blockIdx.x == 0) {
        int run = 0;
        for (int i = 0; i < nb; ++i) { int t = sums[i]; sums[i] = run; run += t; }
    }
}

__global__ __launch_bounds__(256) void scan3_k(const int* __restrict__ part,
        const int* __restrict__ sums, int* __restrict__ ptr, int N, int E) {
    int i = blockIdx.x * 256 + threadIdx.x;
    if (i < N) ptr[i] = part[i] + sums[i >> 11];
    if (i == 0) ptr[N] = E;
}

// ---------------- scatter: atomic-free, single 8B store {src, dst} ----------------
__global__ __launch_bounds__(256) void scatter_k(const int* __restrict__ dst,
        const int* __restrict__ src, const int* __restrict__ ptr,
        const int* __restrict__ rank, int2* __restrict__ csr2, int E) {
    int e = blockIdx.x * 256 + threadIdx.x;
    if (e < E) {
        int d = dst[e];
        int pos = ptr[d] + rank[e];
        csr2[pos] = make_int2(src[e], d);
    }
}

// ---------------- edge weights, layer 1: per-head scalar streams wE[h*E + i] ----------------
__global__ __launch_bounds__(256) void edgew1_k(const int2* __restrict__ csr2,
        const float* __restrict__ ad,
        const float* __restrict__ as_, float* __restrict__ wE, int E) {
    int i = blockIdx.x * 256 + threadIdx.x;
    if (i >= E) return;
    int2 sd = csr2[i];
    int s = sd.x, d = sd.y;
    wE[i]       = lrelu_negexp(ad[d*3+0] + as_[s*3+0]);
    wE[E + i]   = lrelu_negexp(ad[d*3+1] + as_[s*3+1]);
    wE[2*E + i] = lrelu_negexp(ad[d*3+2] + as_[s*3+2]);
}

// ---------------- layer-1 aggregation, ONE HEAD: fp16 gather (2 lines/edge) ----------------
__global__ __launch_bounds__(256) void agg1h_k(const _Float16* __restrict__ h1h,
        const float* __restrict__ wE,
        const int* __restrict__ ptr, const int2* __restrict__ csr2,
        _Float16* __restrict__ out1h, int head, int N) {
    int gt = blockIdx.x * 256 + threadIdx.x;
    int wid = gt >> 6, lane = gt & 63;
    if (wid >= N) return;
    int p0 = ptr[wid], p1 = ptr[wid + 1];
    const _Float16* hbase = h1h + head * 64 + lane;
    float acc = 0.f, den = 0.f;
    int sSafe = csr2[p0].x;

#define G 8
    int s[G]; float w[G], v[G];
#define LD1(i, pos) { if ((pos) < p1) { s[i] = csr2[(pos)].x; w[i] = wE[(pos)]; } \
                      else { s[i] = sSafe; w[i] = 0.f; } }
#pragma unroll
    for (int i = 0; i < G; ++i) LD1(i, p0 + i)
#pragma unroll
    for (int i = 0; i < G; ++i) v[i] = (float)hbase[(size_t)s[i] * 192];

    for (int p = p0; p < p1; p += G) {
        float cv[G], cw[G];
#pragma unroll
        for (int i = 0; i < G; ++i) { cv[i] = v[i]; cw[i] = w[i]; }
        int np = p + G;
        if (np < p1) {
#pragma unroll
            for (int i = 0; i < G; ++i) LD1(i, np + i)
#pragma unroll
            for (int i = 0; i < G; ++i) v[i] = (float)hbase[(size_t)s[i] * 192];
        }
#pragma unroll
        for (int i = 0; i < G; ++i) { acc = fmaf(cw[i], cv[i], acc); den += cw[i]; }
    }
#undef LD1
#undef G
    out1h[(size_t)wid * 192 + head * 64 + lane] = (_Float16)elu1(acc / (den + 1e-16f));
}

// ---------------- GEMM2: h2h[N,64pad] = out1h[N,192] @ Wo[192,40], fp16 in/out ----------------
__global__ __launch_bounds__(256) void gemm2_k(const _Float16* __restrict__ X,
        const float* __restrict__ Wo, _Float16* __restrict__ h2h, int N) {
    __shared__ float Xs[32][193];
    __shared__ float Ws[192 * 40];
    const int tid = threadIdx.x;
    const int row0 = blockIdx.x * 32;
    for (int i = tid; i < 192 * 40; i += 256) Ws[i] = Wo[i];
    for (int i = tid; i < 32 * 48; i += 256) {
        int r = i / 48, c4 = (i % 48) * 4;
        int rr = row0 + r; if (rr >= N) rr = N - 1;
        half4_t v = *(const half4_t*)(X + (size_t)rr * 192 + c4);
        Xs[r][c4+0] = (float)v.x; Xs[r][c4+1] = (float)v.y;
        Xs[r][c4+2] = (float)v.z; Xs[r][c4+3] = (float)v.w;
    }
    __syncthreads();
    int rsub = tid >> 3;
    int f0 = (tid & 7) * 5;
    float acc[5] = {0, 0, 0, 0, 0};
    for (int c = 0; c < 192; ++c) {
        float xv = Xs[rsub][c];
#pragma unroll
        for (int j = 0; j < 5; ++j) acc[j] = fmaf(xv, Ws[c*40 + f0 + j], acc[j]);
    }
    int r = row0 + rsub;
    if (r < N) {
#pragma unroll
        for (int j = 0; j < 5; ++j) h2h[(size_t)r*64 + f0 + j] = (_Float16)acc[j];
    }
}

// ---------------- per-node logit dots, layer 2 (fp16 h2, stride 64) ----------------
__global__ __launch_bounds__(256) void dots2_k(const _Float16* __restrict__ h2h,
        const float* __restrict__ a1o, const float* __restrict__ a2o,
        float* __restrict__ ad2, float* __restrict__ as2, int N) {
    int gt = blockIdx.x * 256 + threadIdx.x;
    int wid = gt >> 6, lane = gt & 63;
    if (wid >= N) return;
    float v = 0.f, w1 = 0.f, w2 = 0.f;
    if (lane < 40) { v = (float)h2h[(size_t)wid*64 + lane]; w1 = a1o[lane]; w2 = a2o[lane]; }
    float da = v * w1, db = v * w2;
#pragma unroll
    for (int o = 32; o > 0; o >>= 1) { da += __shfl_down(da, o, 64); db += __shfl_down(db, o, 64); }
    if (lane == 0) { ad2[wid] = da; as2[wid] = db; }
}

// ---------------- edge weights, layer 2 ----------------
__global__ __launch_bounds__(256) void edgew2_k(const int2* __restrict__ csr2,
        const float* __restrict__ ad2,
        const float* __restrict__ as2, float* __restrict__ w2, int E) {
    int i = blockIdx.x * 256 + threadIdx.x;
    if (i >= E) return;
    int2 sd = csr2[i];
    w2[i] = lrelu_negexp(ad2[sd.y] + as2[sd.x]);
}

// ---------------- layer-2 aggregation: fp16 gather (2 lines/edge), final ELU ----------------
__global__ __launch_bounds__(256) void agg2_k(const _Float16* __restrict__ h2h,
        const float* __restrict__ w2,
        const int* __restrict__ ptr, const int2* __restrict__ csr2,
        float* __restrict__ out, int N) {
    int gt = blockIdx.x * 256 + threadIdx.x;
    int wid = gt >> 6, lane = gt & 63;
    if (wid >= N) return;
    int p0 = ptr[wid], p1 = ptr[wid + 1];
    float acc = 0.f, den = 0.f;
    int sSafe = csr2[p0].x;
    bool act = lane < 40;

#define G 8
    int s[G]; float w[G], v[G];
#define LD2(i, pos) { if ((pos) < p1) { s[i] = csr2[(pos)].x; w[i] = w2[(pos)]; } \
                      else { s[i] = sSafe; w[i] = 0.f; } }
#pragma unroll
    for (int i = 0; i < G; ++i) LD2(i, p0 + i)
#pragma unroll
    for (int i = 0; i < G; ++i) v[i] = act ? (float)h2h[(size_t)s[i] * 64 + lane] : 0.f;

    for (int p = p0; p < p1; p += G) {
        float cv[G], cw[G];
#pragma unroll
        for (int i = 0; i < G; ++i) { cv[i] = v[i]; cw[i] = w[i]; }
        int np = p + G;
        if (np < p1) {
#pragma unroll
            for (int i = 0; i < G; ++i) LD2(i, np + i)
#pragma unroll
            for (int i = 0; i < G; ++i) v[i] = act ? (float)h2h[(size_t)s[i] * 64 + lane] : 0.f;
        }
#pragma unroll
        for (int i = 0; i < G; ++i) { acc = fmaf(cw[i], cv[i], acc); den += cw[i]; }
    }
#undef LD2
#undef G
    float o = elu1(acc / (den + 1e-16f));
    if (act) out[(size_t)wid*40 + lane] = o;
}

extern "C" void kernel_launch(void* const* d_in, const int* in_sizes, int n_in,
                              void* d_out, int out_size, void* d_ws, size_t ws_size,
                              hipStream_t stream) {
    const float* x   = (const float*)d_in[0];
    const int*   ei  = (const int*)d_in[1];
    const float* W   = (const float*)d_in[2];
    const float* a1  = (const float*)d_in[3];
    const float* a2  = (const float*)d_in[4];
    const float* Wo  = (const float*)d_in[5];
    const float* a1o = (const float*)d_in[6];
    const float* a2o = (const float*)d_in[7];
    const int N = in_sizes[0] / NFEAT;
    const int E = in_sizes[1] / 2;
    const int* dst = ei;
    const int* src = ei + E;

    char* base = (char*)d_ws;
    size_t off = 0;
    auto alloc = [&](size_t bytes) { void* p = base + off; off += (bytes + 255) & ~(size_t)255; return p; };
    _Float16* h1h   = (_Float16*)alloc((size_t)N * 192 * 2);   // 38.4 MB
    _Float16* out1h = (_Float16*)alloc((size_t)N * 192 * 2);   // 38.4 MB
    int2*     csr2  = (int2*)alloc((size_t)E * 8);             // 26.5 MB
    int*      rank  = (int*)alloc((size_t)E * 4);              // 13.2 MB
    char*     bufA  = (char*)alloc((size_t)N * NFEAT * 2);     // 51.2 MB: xhi, later h2h+ad2+as2
    char*     bufB  = (char*)alloc((size_t)N * NFEAT * 2);     // 51.2 MB: xlo, later wE/w2
    int*      ptr   = (int*)alloc((size_t)(N + 1) * 4);
    int*      cnt   = (int*)alloc((size_t)N * 4);
    int*      part  = (int*)alloc((size_t)N * 4);
    int*      sums  = (int*)alloc(1024);
    float*    ad1   = (float*)alloc((size_t)N * 3 * 4);
    float*    as1   = (float*)alloc((size_t)N * 3 * 4);
    unsigned short* wthi = (unsigned short*)alloc((size_t)NHEADS * NHID * NFEAT * 2);
    unsigned short* wtlo = (unsigned short*)alloc((size_t)NHEADS * NHID * NFEAT * 2);

    unsigned short* xhi = (unsigned short*)bufA;              // dead after gemm1
    unsigned short* xlo = (unsigned short*)bufB;              // dead after gemm1
    _Float16* h2h = (_Float16*)bufA;                          // N*64*2 = 12.8 MB
    float*    ad2 = (float*)(bufA + (size_t)N * 64 * 2 + 1024);
    float*    as2 = ad2 + N;
    float*    wE  = (float*)bufB;                             // 3*E*4 = 39.7 MB
    float*    w2  = (float*)bufB;                             // layer-2 reuse (after agg1h)

    hipMemsetAsync(cnt, 0, (size_t)N * 4, stream);

    long n4 = (long)N * NFEAT / 4;
    cvt_x_k<<<(int)((n4 + 255) / 256), 256, 0, stream>>>(x, xhi, xlo, n4);
    cvt_w_k<<<(NHEADS * NHID * NFEAT + 255) / 256, 256, 0, stream>>>(W, wthi, wtlo);
    gemm1_mfma_k<<<(N + 127) / 128, 256, 0, stream>>>(xhi, xlo, wthi, wtlo, h1h, N);

    hist_k<<<(E + 255) / 256, 256, 0, stream>>>(dst, cnt, rank, E);
    int nb = (N + 2047) / 2048;
    scan1_k<<<nb, 256, 0, stream>>>(cnt, part, sums, N);
    scan2_k<<<1, 64, 0, stream>>>(sums, nb);
    scan3_k<<<(N + 255) / 256, 256, 0, stream>>>(part, sums, ptr, N, E);
    scatter_k<<<(E + 255) / 256, 256, 0, stream>>>(dst, src, ptr, rank, csr2, E);

    dots1_k<<<(N + 3) / 4, 256, 0, stream>>>(h1h, a1, a2, ad1, as1, N);
    edgew1_k<<<(E + 255) / 256, 256, 0, stream>>>(csr2, ad1, as1, wE, E);
    for (int head = 0; head < NHEADS; ++head)
        agg1h_k<<<(N + 3) / 4, 256, 0, stream>>>(h1h, wE + (size_t)head * E,
                                                 ptr, csr2, out1h, head, N);

    gemm2_k<<<(N + 31) / 32, 256, 0, stream>>>(out1h, Wo, h2h, N);
    dots2_k<<<(N + 3) / 4, 256, 0, stream>>>(h2h, a1o, a2o, ad2, as2, N);
    edgew2_k<<<(E + 255) / 256, 256, 0, stream>>>(csr2, ad2, as2, w2, E);
    agg2_k<<<(N + 3) / 4, 256, 0, stream>>>(h2h, w2, ptr, csr2, (float*)d_out, N);
}